// Round 6
// baseline (295.712 us; speedup 1.0000x reference)
//
#include <hip/hip_runtime.h>

#define NN 100000
#define KK 16
#define DD 128
#define DEE 32
#define DTT 32
#define C1 192        // D + DE + DT
#define BN 32         // nodes per block
#define AB 200        // aggb row stride in shorts; 100 words ≡ 4 mod 32 banks -> 2-way (free)
#define HB 136        // hb row stride in shorts;    68 words ≡ 4 mod 32 banks -> 2-way (free)
#define GRID (NN / BN)

// transformed-weight region: per layer, W1T = 24*128*8 = 24576, W2T = 32*128*8 = 32768
#define W1T_SH 24576
#define WLAYER_SH 57344                  // shorts per layer
#define WTOT_SH (2 * WLAYER_SH)          // 229376 B total
#define TMP_OFF_B 229376                 // bf16 layer-0 out
#define TMP_B (NN * DD * 2)              // 25.6 MB
#define FBF_OFF_B (TMP_OFF_B + TMP_B)    // bf16 features
#define FBF_B (NN * DD * 2)

typedef __attribute__((ext_vector_type(8))) short bfrag;     // 8 bf16 = 4 VGPR (MFMA A/B)
typedef __attribute__((ext_vector_type(4))) float f32x4;     // MFMA C/D
typedef __attribute__((ext_vector_type(4))) short short4v;   // 8-byte chunk
typedef __attribute__((ext_vector_type(4))) unsigned uint4v; // bfrag as 4 dwords

__device__ __forceinline__ short f2bf(float x) {  // RNE f32 -> bf16 bits
  unsigned u = __builtin_bit_cast(unsigned, x);
  unsigned r = u + 0x7fffu + ((u >> 16) & 1u);
  return (short)(r >> 16);
}

// ---- prep: W1/W2 (both layers) -> bf16 fragment-major [kg][col][8] ----
__global__ void prep_weights(const float* __restrict__ W1, const float* __restrict__ W2,
                             short* __restrict__ out) {
  const int t = blockIdx.x * 256 + threadIdx.x;
  const int l = t / WLAYER_SH;
  const int r = t % WLAYER_SH;
  float v;
  if (r < W1T_SH) {
    const int kg = r >> 10, col = (r >> 3) & 127, j = r & 7;
    v = W1[(size_t)l * C1 * DD + (size_t)(kg * 8 + j) * DD + col];
  } else {
    const int r2 = r - W1T_SH;
    const int kg = r2 >> 10, col = (r2 >> 3) & 127, j = r2 & 7;
    v = W2[(size_t)l * 2 * DD * DD + (size_t)(kg * 8 + j) * DD + col];
  }
  out[t] = f2bf(v);
}

// ---- prep: features f32 -> bf16 table ----
__global__ void feat2bf(const float* __restrict__ f, short* __restrict__ o) {
  const size_t i = ((size_t)blockIdx.x * 256 + threadIdx.x) * 4;
  const float4 v = *reinterpret_cast<const float4*>(f + i);
  short4v s; s[0] = f2bf(v.x); s[1] = f2bf(v.y); s[2] = f2bf(v.z); s[3] = f2bf(v.w);
  *reinterpret_cast<short4v*>(o + i) = s;
}

// accumulate 8 bf16 (one bfrag) into 8 f32 accumulators via bit ops
__device__ __forceinline__ void acc_bfrag(float* a, const bfrag v) {
  const uint4v u = __builtin_bit_cast(uint4v, v);
  #pragma unroll
  for (int i = 0; i < 4; ++i) {
    a[2 * i]     += __builtin_bit_cast(float, u[i] << 16);
    a[2 * i + 1] += __builtin_bit_cast(float, u[i] & 0xffff0000u);
  }
}

// ---- fused TGN layer: prev is ALWAYS bf16 [N][128]; OUTBF selects tmp(bf16)/out(f32) ----
template<bool OUTBF>
__global__ __launch_bounds__(256, 7) void tgn(
    const short* __restrict__ prevb,  // bf16 gather table == GEMM2-A rows
    const float* __restrict__ edge,   // [N, K, DE]
    const float* __restrict__ timef,  // [N, K, DT]
    const short* __restrict__ wT,     // [W1T | W2T] bf16 fragment-major
    const float* __restrict__ b1g,    // [128]
    const float* __restrict__ b2g,    // [128]
    const int* __restrict__ idxg,     // [N, K]
    void* __restrict__ out_)          // [N, D]
{
  __shared__ short aggb[BN][AB];   // phase A: [nbr_sum | e_sum | t_sum]; phase B: prev rows
  __shared__ short hb[BN][HB];     // relu(agg@W1+b1)

  const int t  = threadIdx.x;
  const int n0 = blockIdx.x * BN;   // NN % BN == 0
  const int g16  = t & 15;          // lane-in-16-group
  const int nlo  = t >> 4;          // node 0..15 (pass adds +16)
  const int d8   = g16 * 8;         // 16B column offset (shorts)

  // phase 0a: issue this block's own prev rows -> registers (write to LDS after GEMM1)
  const bfrag pv0 = *reinterpret_cast<const bfrag*>(prevb + (size_t)(n0 + nlo) * DD + d8);
  const bfrag pv1 = *reinterpret_cast<const bfrag*>(prevb + (size_t)(n0 + 16 + nlo) * DD + d8);

  // phase 0b: edge/time sums -> aggb[:, 128:192]
  {
    const int c4 = (t & 7) * 4;
    const int nl = t >> 3;  // 0..31
    const float* ep = edge  + (size_t)(n0 + nl) * KK * DEE + c4;
    const float* tp = timef + (size_t)(n0 + nl) * KK * DTT + c4;
    float e0=0,e1=0,e2=0,e3=0, s0=0,s1=0,s2=0,s3=0;
    #pragma unroll
    for (int j = 0; j < KK; ++j) {
      const float4 ev = *reinterpret_cast<const float4*>(ep + j * DEE);
      const float4 tv = *reinterpret_cast<const float4*>(tp + j * DTT);
      e0 += ev.x; e1 += ev.y; e2 += ev.z; e3 += ev.w;
      s0 += tv.x; s1 += tv.y; s2 += tv.z; s3 += tv.w;
    }
    short4v eo; eo[0]=f2bf(e0); eo[1]=f2bf(e1); eo[2]=f2bf(e2); eo[3]=f2bf(e3);
    short4v so; so[0]=f2bf(s0); so[1]=f2bf(s1); so[2]=f2bf(s2); so[3]=f2bf(s3);
    *reinterpret_cast<short4v*>(&aggb[nl][DD + c4])       = eo;
    *reinterpret_cast<short4v*>(&aggb[nl][DD + DEE + c4]) = so;
  }

  // phase 0c: neighbor gather-sum, 16B/lane -> aggb[:, 0:128]
  {
    #pragma unroll
    for (int p = 0; p < 2; ++p) {
      const int nl = nlo + p * 16;
      const int4* ip = reinterpret_cast<const int4*>(idxg + (size_t)(n0 + nl) * KK);
      const int4 i0 = ip[0], i1 = ip[1], i2 = ip[2], i3 = ip[3];
      const int rows[16] = {i0.x, i0.y, i0.z, i0.w, i1.x, i1.y, i1.z, i1.w,
                            i2.x, i2.y, i2.z, i2.w, i3.x, i3.y, i3.z, i3.w};
      float a[8] = {0.f, 0.f, 0.f, 0.f, 0.f, 0.f, 0.f, 0.f};
      #pragma unroll
      for (int j = 0; j < 16; ++j) {
        const bfrag v = *reinterpret_cast<const bfrag*>(prevb + (size_t)rows[j] * DD + d8);
        acc_bfrag(a, v);
      }
      bfrag o;
      #pragma unroll
      for (int i = 0; i < 8; ++i) o[i] = f2bf(a[i]);
      *reinterpret_cast<bfrag*>(&aggb[nl][d8]) = o;
    }
  }
  __syncthreads();  // aggb (sums) ready

  const int lane = t & 63;
  const int wv   = t >> 6;
  const int lr   = lane & 15;
  const int lg   = lane >> 4;
  const int n0w  = wv * 32;

  // ---- GEMM1: h = relu(aggb @ W1 + b1) -> hb ----
  {
    f32x4 acc[2][2];
    #pragma unroll
    for (int nt = 0; nt < 2; ++nt) {
      const float bv = b1g[n0w + nt * 16 + lr];
      acc[0][nt] = (f32x4){bv, bv, bv, bv};
      acc[1][nt] = (f32x4){bv, bv, bv, bv};
    }
    #pragma unroll
    for (int ks = 0; ks < 6; ++ks) {
      const bfrag a0 = *reinterpret_cast<const bfrag*>(&aggb[lr][ks * 32 + lg * 8]);
      const bfrag a1 = *reinterpret_cast<const bfrag*>(&aggb[16 + lr][ks * 32 + lg * 8]);
      const short* wp = wT + ((size_t)((ks * 4 + lg) * 128) + n0w + lr) * 8;
      const bfrag bb0 = *reinterpret_cast<const bfrag*>(wp);
      const bfrag bb1 = *reinterpret_cast<const bfrag*>(wp + 16 * 8);
      acc[0][0] = __builtin_amdgcn_mfma_f32_16x16x32_bf16(a0, bb0, acc[0][0], 0, 0, 0);
      acc[1][0] = __builtin_amdgcn_mfma_f32_16x16x32_bf16(a1, bb0, acc[1][0], 0, 0, 0);
      acc[0][1] = __builtin_amdgcn_mfma_f32_16x16x32_bf16(a0, bb1, acc[0][1], 0, 0, 0);
      acc[1][1] = __builtin_amdgcn_mfma_f32_16x16x32_bf16(a1, bb1, acc[1][1], 0, 0, 0);
    }
    #pragma unroll
    for (int mt = 0; mt < 2; ++mt)
      #pragma unroll
      for (int nt = 0; nt < 2; ++nt)
        #pragma unroll
        for (int r = 0; r < 4; ++r)
          hb[mt * 16 + lg * 4 + r][n0w + nt * 16 + lr] = f2bf(fmaxf(acc[mt][nt][r], 0.f));
  }
  __syncthreads();  // all aggb reads done; hb ready

  // phase B: write prev rows (held in regs since phase 0a) into aggb[:, 0:128]
  *reinterpret_cast<bfrag*>(&aggb[nlo][d8])      = pv0;
  *reinterpret_cast<bfrag*>(&aggb[16 + nlo][d8]) = pv1;
  __syncthreads();  // aggb (prev) ready

  // ---- GEMM2: out = [prev | h] @ W2 + b2 (all-LDS A operands) ----
  {
    const short* w2T = wT + W1T_SH;
    f32x4 acc[2][2];
    #pragma unroll
    for (int nt = 0; nt < 2; ++nt) {
      const float bv = b2g[n0w + nt * 16 + lr];
      acc[0][nt] = (f32x4){bv, bv, bv, bv};
      acc[1][nt] = (f32x4){bv, bv, bv, bv};
    }
    #pragma unroll
    for (int ks = 0; ks < 8; ++ks) {
      bfrag a0, a1;
      if (ks < 4) {
        a0 = *reinterpret_cast<const bfrag*>(&aggb[lr][ks * 32 + lg * 8]);
        a1 = *reinterpret_cast<const bfrag*>(&aggb[16 + lr][ks * 32 + lg * 8]);
      } else {
        a0 = *reinterpret_cast<const bfrag*>(&hb[lr][(ks - 4) * 32 + lg * 8]);
        a1 = *reinterpret_cast<const bfrag*>(&hb[16 + lr][(ks - 4) * 32 + lg * 8]);
      }
      const short* wp = w2T + ((size_t)((ks * 4 + lg) * 128) + n0w + lr) * 8;
      const bfrag bb0 = *reinterpret_cast<const bfrag*>(wp);
      const bfrag bb1 = *reinterpret_cast<const bfrag*>(wp + 16 * 8);
      acc[0][0] = __builtin_amdgcn_mfma_f32_16x16x32_bf16(a0, bb0, acc[0][0], 0, 0, 0);
      acc[1][0] = __builtin_amdgcn_mfma_f32_16x16x32_bf16(a1, bb0, acc[1][0], 0, 0, 0);
      acc[0][1] = __builtin_amdgcn_mfma_f32_16x16x32_bf16(a0, bb1, acc[0][1], 0, 0, 0);
      acc[1][1] = __builtin_amdgcn_mfma_f32_16x16x32_bf16(a1, bb1, acc[1][1], 0, 0, 0);
    }
    #pragma unroll
    for (int mt = 0; mt < 2; ++mt)
      #pragma unroll
      for (int nt = 0; nt < 2; ++nt)
        #pragma unroll
        for (int r = 0; r < 4; ++r) {
          const float v = acc[mt][nt][r];
          const size_t grow = (size_t)(n0 + mt * 16 + lg * 4 + r);
          const int    gcol = n0w + nt * 16 + lr;
          if constexpr (OUTBF) ((short*)out_)[grow * DD + gcol] = f2bf(v);
          else                 ((float*)out_)[grow * DD + gcol] = v;
        }
  }
}

extern "C" void kernel_launch(void* const* d_in, const int* in_sizes, int n_in,
                              void* d_out, int out_size, void* d_ws, size_t ws_size,
                              hipStream_t stream) {
  const float* features = (const float*)d_in[0];
  const float* edge     = (const float*)d_in[1];
  const float* timef    = (const float*)d_in[2];
  const float* W1       = (const float*)d_in[3];
  const float* b1       = (const float*)d_in[4];
  const float* W2       = (const float*)d_in[5];
  const float* b2       = (const float*)d_in[6];
  const int*   idx      = (const int*)d_in[7];
  float* outp = (float*)d_out;

  short* wT     = (short*)d_ws;
  short* tmp    = (short*)((char*)d_ws + TMP_OFF_B);
  short* featbf = (short*)((char*)d_ws + FBF_OFF_B);

  dim3 block(256);

  prep_weights<<<dim3(WTOT_SH / 256), block, 0, stream>>>(W1, W2, wT);
  feat2bf<<<dim3(NN * DD / 4 / 256), block, 0, stream>>>(features, featbf);

  // layer 0: featbf -> tmp (bf16)
  tgn<true><<<dim3(GRID), block, 0, stream>>>(
      featbf, edge, timef, wT, b1, b2, idx, tmp);

  // layer 1: tmp -> out (f32)
  tgn<false><<<dim3(GRID), block, 0, stream>>>(
      tmp,
      edge  + (size_t)NN * KK * DEE,
      timef + (size_t)NN * KK * DTT,
      wT + WLAYER_SH,
      b1 + DD,
      b2 + DD,
      idx + (size_t)NN * KK,
      outp);
}

// Round 7
// 277.386 us; speedup vs baseline: 1.0661x; 1.0661x over previous
//
#include <hip/hip_runtime.h>

#define NN 100000
#define KK 16
#define DD 128
#define DEE 32
#define DTT 32
#define C1 192        // D + DE + DT
#define BN 32         // nodes per block
#define AB 200        // aggb row stride in shorts; ≡4 words mod 32 banks -> 2-way (free)
#define A2B 264       // a2b row stride in shorts; ≡4 words mod 32 banks -> 2-way (free)
#define GRID (NN / BN)

// ws layout
#define W1T_SH 24576                     // per layer: 24*128*8
#define WLAYER_SH 57344                  // shorts per layer (W1T + W2T)
#define WTOT_SH (2 * WLAYER_SH)          // 229376 B total
#define TMP_OFF_B 229376                 // bf16 layer-0 out
#define TMP_B (NN * DD * 2)              // 25.6 MB
#define FBF_OFF_B (TMP_OFF_B + TMP_B)    // bf16 features
#define FBF_B (NN * DD * 2)              // 25.6 MB
#define SUMS_OFF_B (FBF_OFF_B + FBF_B)   // bf16 layer-1 presums [N][64]
#define SUMS_B (NN * 64 * 2)             // 12.8 MB

#define FBF_BLOCKS (NN * DD / 4 / 256)   // 12500
#define PREP_BLOCKS (WTOT_SH / 256)      // 448

typedef __attribute__((ext_vector_type(8))) short bfrag;    // 8 bf16 = 4 VGPR (MFMA A/B)
typedef __attribute__((ext_vector_type(4))) float f32x4;    // MFMA C/D
typedef __attribute__((ext_vector_type(4))) short short4v;  // 8-byte chunk

__device__ __forceinline__ short f2bf(float x) {  // RNE f32 -> bf16 bits
  unsigned u = __builtin_bit_cast(unsigned, x);
  unsigned r = u + 0x7fffu + ((u >> 16) & 1u);
  return (short)(r >> 16);
}
__device__ __forceinline__ float bf2f(short s) {
  unsigned u = ((unsigned)(unsigned short)s) << 16;
  return __builtin_bit_cast(float, u);
}

// ---- merged prep: features f32->bf16 table, then W1/W2 -> bf16 fragment-major ----
__global__ void prep_all(const float* __restrict__ f, short* __restrict__ fo,
                         const float* __restrict__ W1, const float* __restrict__ W2,
                         short* __restrict__ wo) {
  const int b = blockIdx.x;
  if (b < FBF_BLOCKS) {
    const size_t i = ((size_t)b * 256 + threadIdx.x) * 4;
    const float4 v = *reinterpret_cast<const float4*>(f + i);
    short4v s; s[0] = f2bf(v.x); s[1] = f2bf(v.y); s[2] = f2bf(v.z); s[3] = f2bf(v.w);
    *reinterpret_cast<short4v*>(fo + i) = s;
    return;
  }
  const int t = (b - FBF_BLOCKS) * 256 + threadIdx.x;
  const int l = t / WLAYER_SH;
  const int r = t % WLAYER_SH;
  float v;
  if (r < W1T_SH) {
    const int kg = r >> 10, col = (r >> 3) & 127, j = r & 7;
    v = W1[(size_t)l * C1 * DD + (size_t)(kg * 8 + j) * DD + col];
  } else {
    const int r2 = r - W1T_SH;
    const int kg = r2 >> 10, col = (r2 >> 3) & 127, j = r2 & 7;
    v = W2[(size_t)l * 2 * DD * DD + (size_t)(kg * 8 + j) * DD + col];
  }
  wo[t] = f2bf(v);
}

// ---- fused TGN layer (round-3 structure). PRESUM: e/t sums precomputed.
// EPI: stream next layer's edge/time rows for this block's nodes -> presums.
template<bool OUTBF, bool PRESUM, bool EPI>
__global__ __launch_bounds__(256, 5) void tgn(
    const short* __restrict__ prevb,  // bf16 gather table == GEMM2-A rows
    const float* __restrict__ edge,   // this layer [N, K, DE] (unused if PRESUM)
    const float* __restrict__ timef,  // this layer [N, K, DT] (unused if PRESUM)
    const short* __restrict__ sums_in,  // presums for this layer (if PRESUM)
    const float* __restrict__ edgeN,  // next layer edge (if EPI)
    const float* __restrict__ timeN,  // next layer time (if EPI)
    short* __restrict__ sums_out,     // presums out (if EPI)
    const short* __restrict__ wT,     // [W1T | W2T] bf16 fragment-major
    const float* __restrict__ b1g,    // [128]
    const float* __restrict__ b2g,    // [128]
    const int* __restrict__ idxg,     // [N, K]
    void* __restrict__ out_)          // [N, D]
{
  __shared__ short aggb[BN][AB];   // [nbr_sum | e_sum | t_sum], K=192
  __shared__ short a2b[BN][A2B];   // [prev | h], K=256

  const int t  = threadIdx.x;
  const int n0 = blockIdx.x * BN;   // NN % BN == 0

  // phase 0a: stage this block's own prev rows -> a2b[:, 0:128]
  {
    const int d4 = (t & 31) * 4;
    for (int nl = t >> 5; nl < BN; nl += 8) {
      const short4v o = *reinterpret_cast<const short4v*>(prevb + (size_t)(n0 + nl) * DD + d4);
      *reinterpret_cast<short4v*>(&a2b[nl][d4]) = o;
    }
  }

  // phase 0b: edge/time sums -> aggb[:, 128:192]
  if constexpr (PRESUM) {
    const bfrag s = *reinterpret_cast<const bfrag*>(sums_in + (size_t)n0 * 64 + t * 8);
    *reinterpret_cast<bfrag*>(&aggb[t >> 3][DD + (t & 7) * 8]) = s;
  } else {
    const int c4 = (t & 7) * 4;
    const int nl = t >> 3;  // 0..31
    const float* ep = edge  + (size_t)(n0 + nl) * KK * DEE + c4;
    const float* tp = timef + (size_t)(n0 + nl) * KK * DTT + c4;
    float e0=0,e1=0,e2=0,e3=0, s0=0,s1=0,s2=0,s3=0;
    #pragma unroll
    for (int j = 0; j < KK; ++j) {
      const float4 ev = *reinterpret_cast<const float4*>(ep + j * DEE);
      const float4 tv = *reinterpret_cast<const float4*>(tp + j * DTT);
      e0 += ev.x; e1 += ev.y; e2 += ev.z; e3 += ev.w;
      s0 += tv.x; s1 += tv.y; s2 += tv.z; s3 += tv.w;
    }
    short4v eo; eo[0]=f2bf(e0); eo[1]=f2bf(e1); eo[2]=f2bf(e2); eo[3]=f2bf(e3);
    short4v so; so[0]=f2bf(s0); so[1]=f2bf(s1); so[2]=f2bf(s2); so[3]=f2bf(s3);
    *reinterpret_cast<short4v*>(&aggb[nl][DD + c4])       = eo;
    *reinterpret_cast<short4v*>(&aggb[nl][DD + DEE + c4]) = so;
  }

  // phase 0c: neighbor gather-sum (bf16 rows, 8B/lane) -> aggb[:, 0:128]
  {
    const int d4 = (t & 31) * 4;
    for (int nl = t >> 5; nl < BN; nl += 8) {
      const int4* ip = reinterpret_cast<const int4*>(idxg + (size_t)(n0 + nl) * KK);
      const int4 i0 = ip[0], i1 = ip[1], i2 = ip[2], i3 = ip[3];
      const int rows[16] = {i0.x, i0.y, i0.z, i0.w, i1.x, i1.y, i1.z, i1.w,
                            i2.x, i2.y, i2.z, i2.w, i3.x, i3.y, i3.z, i3.w};
      float a0=0, a1=0, a2=0, a3=0;
      #pragma unroll
      for (int j = 0; j < 16; ++j) {
        const short4v v = *reinterpret_cast<const short4v*>(prevb + (size_t)rows[j] * DD + d4);
        a0 += bf2f(v[0]); a1 += bf2f(v[1]); a2 += bf2f(v[2]); a3 += bf2f(v[3]);
      }
      short4v o; o[0]=f2bf(a0); o[1]=f2bf(a1); o[2]=f2bf(a2); o[3]=f2bf(a3);
      *reinterpret_cast<short4v*>(&aggb[nl][d4]) = o;
    }
  }
  __syncthreads();  // aggb + a2b[:,0:128] ready

  const int lane = t & 63;
  const int wv   = t >> 6;
  const int lr   = lane & 15;
  const int lg   = lane >> 4;
  const int n0w  = wv * 32;

  // ---- GEMM1: h = relu(aggb @ W1 + b1) -> a2b[:, 128:256] ----
  {
    f32x4 acc[2][2];
    #pragma unroll
    for (int nt = 0; nt < 2; ++nt) {
      const float bv = b1g[n0w + nt * 16 + lr];
      acc[0][nt] = (f32x4){bv, bv, bv, bv};
      acc[1][nt] = (f32x4){bv, bv, bv, bv};
    }
    #pragma unroll
    for (int ks = 0; ks < 6; ++ks) {
      const bfrag a0 = *reinterpret_cast<const bfrag*>(&aggb[lr][ks * 32 + lg * 8]);
      const bfrag a1 = *reinterpret_cast<const bfrag*>(&aggb[16 + lr][ks * 32 + lg * 8]);
      const short* wp = wT + ((size_t)((ks * 4 + lg) * 128) + n0w + lr) * 8;
      const bfrag bb0 = *reinterpret_cast<const bfrag*>(wp);
      const bfrag bb1 = *reinterpret_cast<const bfrag*>(wp + 16 * 8);
      acc[0][0] = __builtin_amdgcn_mfma_f32_16x16x32_bf16(a0, bb0, acc[0][0], 0, 0, 0);
      acc[1][0] = __builtin_amdgcn_mfma_f32_16x16x32_bf16(a1, bb0, acc[1][0], 0, 0, 0);
      acc[0][1] = __builtin_amdgcn_mfma_f32_16x16x32_bf16(a0, bb1, acc[0][1], 0, 0, 0);
      acc[1][1] = __builtin_amdgcn_mfma_f32_16x16x32_bf16(a1, bb1, acc[1][1], 0, 0, 0);
    }
    #pragma unroll
    for (int mt = 0; mt < 2; ++mt)
      #pragma unroll
      for (int nt = 0; nt < 2; ++nt)
        #pragma unroll
        for (int r = 0; r < 4; ++r)
          a2b[mt * 16 + lg * 4 + r][DD + n0w + nt * 16 + lr] = f2bf(fmaxf(acc[mt][nt][r], 0.f));
  }
  __syncthreads();  // a2b (prev|h) ready

  // ---- GEMM2: out = a2b @ W2 + b2 ----
  {
    const short* w2T = wT + W1T_SH;
    f32x4 acc[2][2];
    #pragma unroll
    for (int nt = 0; nt < 2; ++nt) {
      const float bv = b2g[n0w + nt * 16 + lr];
      acc[0][nt] = (f32x4){bv, bv, bv, bv};
      acc[1][nt] = (f32x4){bv, bv, bv, bv};
    }
    #pragma unroll
    for (int ks = 0; ks < 8; ++ks) {
      const bfrag a0 = *reinterpret_cast<const bfrag*>(&a2b[lr][ks * 32 + lg * 8]);
      const bfrag a1 = *reinterpret_cast<const bfrag*>(&a2b[16 + lr][ks * 32 + lg * 8]);
      const short* wp = w2T + ((size_t)((ks * 4 + lg) * 128) + n0w + lr) * 8;
      const bfrag bb0 = *reinterpret_cast<const bfrag*>(wp);
      const bfrag bb1 = *reinterpret_cast<const bfrag*>(wp + 16 * 8);
      acc[0][0] = __builtin_amdgcn_mfma_f32_16x16x32_bf16(a0, bb0, acc[0][0], 0, 0, 0);
      acc[1][0] = __builtin_amdgcn_mfma_f32_16x16x32_bf16(a1, bb0, acc[1][0], 0, 0, 0);
      acc[0][1] = __builtin_amdgcn_mfma_f32_16x16x32_bf16(a0, bb1, acc[0][1], 0, 0, 0);
      acc[1][1] = __builtin_amdgcn_mfma_f32_16x16x32_bf16(a1, bb1, acc[1][1], 0, 0, 0);
    }
    #pragma unroll
    for (int mt = 0; mt < 2; ++mt)
      #pragma unroll
      for (int nt = 0; nt < 2; ++nt)
        #pragma unroll
        for (int r = 0; r < 4; ++r) {
          const float v = acc[mt][nt][r];
          const size_t grow = (size_t)(n0 + mt * 16 + lg * 4 + r);
          const int    gcol = n0w + nt * 16 + lr;
          if constexpr (OUTBF) ((short*)out_)[grow * DD + gcol] = f2bf(v);
          else                 ((float*)out_)[grow * DD + gcol] = v;
        }
  }

  // ---- epilogue: stream NEXT layer's edge/time rows for this block's nodes ----
  if constexpr (EPI) {
    const int c4 = (t & 7) * 4;
    const int nl = t >> 3;  // 0..31
    const int n  = n0 + nl;
    const float* ep = edgeN + (size_t)n * KK * DEE + c4;
    const float* tp = timeN + (size_t)n * KK * DTT + c4;
    float e0=0,e1=0,e2=0,e3=0, s0=0,s1=0,s2=0,s3=0;
    #pragma unroll
    for (int j = 0; j < KK; ++j) {
      const float4 ev = *reinterpret_cast<const float4*>(ep + j * DEE);
      const float4 tv = *reinterpret_cast<const float4*>(tp + j * DTT);
      e0 += ev.x; e1 += ev.y; e2 += ev.z; e3 += ev.w;
      s0 += tv.x; s1 += tv.y; s2 += tv.z; s3 += tv.w;
    }
    short4v eo; eo[0]=f2bf(e0); eo[1]=f2bf(e1); eo[2]=f2bf(e2); eo[3]=f2bf(e3);
    short4v so; so[0]=f2bf(s0); so[1]=f2bf(s1); so[2]=f2bf(s2); so[3]=f2bf(s3);
    *reinterpret_cast<short4v*>(sums_out + (size_t)n * 64 + c4)      = eo;
    *reinterpret_cast<short4v*>(sums_out + (size_t)n * 64 + 32 + c4) = so;
  }
}

extern "C" void kernel_launch(void* const* d_in, const int* in_sizes, int n_in,
                              void* d_out, int out_size, void* d_ws, size_t ws_size,
                              hipStream_t stream) {
  const float* features = (const float*)d_in[0];
  const float* edge     = (const float*)d_in[1];
  const float* timef    = (const float*)d_in[2];
  const float* W1       = (const float*)d_in[3];
  const float* b1       = (const float*)d_in[4];
  const float* W2       = (const float*)d_in[5];
  const float* b2       = (const float*)d_in[6];
  const int*   idx      = (const int*)d_in[7];
  float* outp = (float*)d_out;

  short* wT     = (short*)d_ws;
  short* tmp    = (short*)((char*)d_ws + TMP_OFF_B);
  short* featbf = (short*)((char*)d_ws + FBF_OFF_B);
  short* sums1  = (short*)((char*)d_ws + SUMS_OFF_B);

  const float* edge1 = edge  + (size_t)NN * KK * DEE;
  const float* time1 = timef + (size_t)NN * KK * DTT;

  dim3 block(256);

  prep_all<<<dim3(FBF_BLOCKS + PREP_BLOCKS), block, 0, stream>>>(
      features, featbf, W1, W2, wT);

  // layer 0: featbf -> tmp (bf16); streams L0 e/t, epilogue streams L1 e/t -> sums1
  tgn<true, false, true><<<dim3(GRID), block, 0, stream>>>(
      featbf, edge, timef, nullptr, edge1, time1, sums1,
      wT, b1, b2, idx, tmp);

  // layer 1: tmp -> out (f32); no streaming, uses sums1
  tgn<false, true, false><<<dim3(GRID), block, 0, stream>>>(
      tmp, nullptr, nullptr, sums1, nullptr, nullptr, nullptr,
      wT + WLAYER_SH, b1 + DD, b2 + DD,
      idx + (size_t)NN * KK, outp);
}

// Round 9
// 258.147 us; speedup vs baseline: 1.1455x; 1.0745x over previous
//
#include <hip/hip_runtime.h>

#define NN 100000
#define KK 16
#define DD 128
#define DEE 32
#define DTT 32
#define C1 192        // D + DE + DT
#define BN 32         // nodes per block
#define AB 200        // aggb row stride in shorts; ≡4 words mod 32 banks -> 2-way (free)
#define A2B 264       // a2b row stride in shorts; ≡4 words mod 32 banks -> 2-way (free)
#define GRID (NN / BN)

// ws layout
#define W1T_SH 24576                     // per layer: 24*128*8
#define WLAYER_SH 57344                  // shorts per layer (W1T + W2T)
#define WTOT_SH (2 * WLAYER_SH)          // 229376 B total
#define TMP_OFF_B 229376                 // bf16 layer-0 out
#define TMP_B (NN * DD * 2)              // 25.6 MB
#define FBF_OFF_B (TMP_OFF_B + TMP_B)    // bf16 features
#define FBF_B (NN * DD * 2)              // 25.6 MB

#define FBF_BLOCKS (NN * DD / 4 / 256)   // 12500
#define PREP_BLOCKS (WTOT_SH / 256)      // 448

typedef __attribute__((ext_vector_type(8))) short bfrag;    // 8 bf16 = 4 VGPR (MFMA A/B)
typedef __attribute__((ext_vector_type(4))) float f32x4;    // MFMA C/D + NT-loadable vec4
typedef __attribute__((ext_vector_type(4))) short short4v;  // 8-byte chunk

__device__ __forceinline__ short f2bf(float x) {  // RNE f32 -> bf16 bits
  unsigned u = __builtin_bit_cast(unsigned, x);
  unsigned r = u + 0x7fffu + ((u >> 16) & 1u);
  return (short)(r >> 16);
}
__device__ __forceinline__ float bf2f(short s) {
  unsigned u = ((unsigned)(unsigned short)s) << 16;
  return __builtin_bit_cast(float, u);
}

// ---- merged prep: features f32->bf16 table, then W1/W2 -> bf16 fragment-major ----
__global__ void prep_all(const float* __restrict__ f, short* __restrict__ fo,
                         const float* __restrict__ W1, const float* __restrict__ W2,
                         short* __restrict__ wo) {
  const int b = blockIdx.x;
  if (b < FBF_BLOCKS) {
    const size_t i = ((size_t)b * 256 + threadIdx.x) * 4;
    const f32x4 v = *reinterpret_cast<const f32x4*>(f + i);
    short4v s; s[0] = f2bf(v[0]); s[1] = f2bf(v[1]); s[2] = f2bf(v[2]); s[3] = f2bf(v[3]);
    *reinterpret_cast<short4v*>(fo + i) = s;
    return;
  }
  const int t = (b - FBF_BLOCKS) * 256 + threadIdx.x;
  const int l = t / WLAYER_SH;
  const int r = t % WLAYER_SH;
  float v;
  if (r < W1T_SH) {
    const int kg = r >> 10, col = (r >> 3) & 127, j = r & 7;
    v = W1[(size_t)l * C1 * DD + (size_t)(kg * 8 + j) * DD + col];
  } else {
    const int r2 = r - W1T_SH;
    const int kg = r2 >> 10, col = (r2 >> 3) & 127, j = r2 & 7;
    v = W2[(size_t)l * 2 * DD * DD + (size_t)(kg * 8 + j) * DD + col];
  }
  wo[t] = f2bf(v);
}

// ---- fused TGN layer (R3 structure + nt streams + dual-row gather) ----
template<bool OUTBF>
__global__ __launch_bounds__(256, 5) void tgn(
    const short* __restrict__ prevb,  // bf16 gather table == GEMM2-A rows
    const float* __restrict__ edge,   // [N, K, DE]
    const float* __restrict__ timef,  // [N, K, DT]
    const short* __restrict__ wT,     // [W1T | W2T] bf16 fragment-major
    const float* __restrict__ b1g,    // [128]
    const float* __restrict__ b2g,    // [128]
    const int* __restrict__ idxg,     // [N, K]
    void* __restrict__ out_)          // [N, D]
{
  __shared__ short aggb[BN][AB];   // [nbr_sum | e_sum | t_sum], K=192
  __shared__ short a2b[BN][A2B];   // [prev | h], K=256

  const int t  = threadIdx.x;
  const int n0 = blockIdx.x * BN;   // NN % BN == 0

  // phase 0a: stage this block's own prev rows -> a2b[:, 0:128]
  {
    const int d4 = (t & 31) * 4;
    for (int nl = t >> 5; nl < BN; nl += 8) {
      const short4v o = *reinterpret_cast<const short4v*>(prevb + (size_t)(n0 + nl) * DD + d4);
      *reinterpret_cast<short4v*>(&a2b[nl][d4]) = o;
    }
  }

  // phase 0b: edge/time sums -> aggb[:, 128:192]  (non-temporal: read-once stream)
  {
    const int c4 = (t & 7) * 4;
    const int nl = t >> 3;  // 0..31
    const f32x4* ep = reinterpret_cast<const f32x4*>(edge  + (size_t)(n0 + nl) * KK * DEE + c4);
    const f32x4* tp = reinterpret_cast<const f32x4*>(timef + (size_t)(n0 + nl) * KK * DTT + c4);
    float e0=0,e1=0,e2=0,e3=0, s0=0,s1=0,s2=0,s3=0;
    #pragma unroll
    for (int j = 0; j < KK; ++j) {
      const f32x4 ev = __builtin_nontemporal_load(ep + j * (DEE / 4));
      const f32x4 tv = __builtin_nontemporal_load(tp + j * (DTT / 4));
      e0 += ev[0]; e1 += ev[1]; e2 += ev[2]; e3 += ev[3];
      s0 += tv[0]; s1 += tv[1]; s2 += tv[2]; s3 += tv[3];
    }
    short4v eo; eo[0]=f2bf(e0); eo[1]=f2bf(e1); eo[2]=f2bf(e2); eo[3]=f2bf(e3);
    short4v so; so[0]=f2bf(s0); so[1]=f2bf(s1); so[2]=f2bf(s2); so[3]=f2bf(s3);
    *reinterpret_cast<short4v*>(&aggb[nl][DD + c4])       = eo;
    *reinterpret_cast<short4v*>(&aggb[nl][DD + DEE + c4]) = so;
  }

  // phase 0c: neighbor gather-sum, two rows in flight per thread -> aggb[:, 0:128]
  {
    const int d4 = (t & 31) * 4;
    const int nr = t >> 5;  // 0..7
    #pragma unroll
    for (int p = 0; p < 2; ++p) {
      const int nlA = nr + p * 16;
      const int nlB = nlA + 8;
      const int4* ipA = reinterpret_cast<const int4*>(idxg + (size_t)(n0 + nlA) * KK);
      const int4* ipB = reinterpret_cast<const int4*>(idxg + (size_t)(n0 + nlB) * KK);
      const int4 a0i = ipA[0], a1i = ipA[1], a2i = ipA[2], a3i = ipA[3];
      const int4 b0i = ipB[0], b1i = ipB[1], b2i = ipB[2], b3i = ipB[3];
      const int rowsA[16] = {a0i.x, a0i.y, a0i.z, a0i.w, a1i.x, a1i.y, a1i.z, a1i.w,
                             a2i.x, a2i.y, a2i.z, a2i.w, a3i.x, a3i.y, a3i.z, a3i.w};
      const int rowsB[16] = {b0i.x, b0i.y, b0i.z, b0i.w, b1i.x, b1i.y, b1i.z, b1i.w,
                             b2i.x, b2i.y, b2i.z, b2i.w, b3i.x, b3i.y, b3i.z, b3i.w};
      float aA0=0, aA1=0, aA2=0, aA3=0;
      float aB0=0, aB1=0, aB2=0, aB3=0;
      #pragma unroll
      for (int j = 0; j < 16; ++j) {
        const short4v vA = *reinterpret_cast<const short4v*>(prevb + (size_t)rowsA[j] * DD + d4);
        const short4v vB = *reinterpret_cast<const short4v*>(prevb + (size_t)rowsB[j] * DD + d4);
        aA0 += bf2f(vA[0]); aA1 += bf2f(vA[1]); aA2 += bf2f(vA[2]); aA3 += bf2f(vA[3]);
        aB0 += bf2f(vB[0]); aB1 += bf2f(vB[1]); aB2 += bf2f(vB[2]); aB3 += bf2f(vB[3]);
      }
      short4v oA; oA[0]=f2bf(aA0); oA[1]=f2bf(aA1); oA[2]=f2bf(aA2); oA[3]=f2bf(aA3);
      short4v oB; oB[0]=f2bf(aB0); oB[1]=f2bf(aB1); oB[2]=f2bf(aB2); oB[3]=f2bf(aB3);
      *reinterpret_cast<short4v*>(&aggb[nlA][d4]) = oA;
      *reinterpret_cast<short4v*>(&aggb[nlB][d4]) = oB;
    }
  }
  __syncthreads();  // aggb + a2b[:,0:128] ready

  const int lane = t & 63;
  const int wv   = t >> 6;
  const int lr   = lane & 15;
  const int lg   = lane >> 4;
  const int n0w  = wv * 32;

  // ---- GEMM1: h = relu(aggb @ W1 + b1) -> a2b[:, 128:256] ----
  {
    f32x4 acc[2][2];
    #pragma unroll
    for (int nt = 0; nt < 2; ++nt) {
      const float bv = b1g[n0w + nt * 16 + lr];
      acc[0][nt] = (f32x4){bv, bv, bv, bv};
      acc[1][nt] = (f32x4){bv, bv, bv, bv};
    }
    #pragma unroll
    for (int ks = 0; ks < 6; ++ks) {
      const bfrag a0 = *reinterpret_cast<const bfrag*>(&aggb[lr][ks * 32 + lg * 8]);
      const bfrag a1 = *reinterpret_cast<const bfrag*>(&aggb[16 + lr][ks * 32 + lg * 8]);
      const short* wp = wT + ((size_t)((ks * 4 + lg) * 128) + n0w + lr) * 8;
      const bfrag bb0 = *reinterpret_cast<const bfrag*>(wp);
      const bfrag bb1 = *reinterpret_cast<const bfrag*>(wp + 16 * 8);
      acc[0][0] = __builtin_amdgcn_mfma_f32_16x16x32_bf16(a0, bb0, acc[0][0], 0, 0, 0);
      acc[1][0] = __builtin_amdgcn_mfma_f32_16x16x32_bf16(a1, bb0, acc[1][0], 0, 0, 0);
      acc[0][1] = __builtin_amdgcn_mfma_f32_16x16x32_bf16(a0, bb1, acc[0][1], 0, 0, 0);
      acc[1][1] = __builtin_amdgcn_mfma_f32_16x16x32_bf16(a1, bb1, acc[1][1], 0, 0, 0);
    }
    #pragma unroll
    for (int mt = 0; mt < 2; ++mt)
      #pragma unroll
      for (int nt = 0; nt < 2; ++nt)
        #pragma unroll
        for (int r = 0; r < 4; ++r)
          a2b[mt * 16 + lg * 4 + r][DD + n0w + nt * 16 + lr] = f2bf(fmaxf(acc[mt][nt][r], 0.f));
  }
  __syncthreads();  // a2b (prev|h) ready

  // ---- GEMM2: out = a2b @ W2 + b2 ----
  {
    const short* w2T = wT + W1T_SH;
    f32x4 acc[2][2];
    #pragma unroll
    for (int nt = 0; nt < 2; ++nt) {
      const float bv = b2g[n0w + nt * 16 + lr];
      acc[0][nt] = (f32x4){bv, bv, bv, bv};
      acc[1][nt] = (f32x4){bv, bv, bv, bv};
    }
    #pragma unroll
    for (int ks = 0; ks < 8; ++ks) {
      const bfrag a0 = *reinterpret_cast<const bfrag*>(&a2b[lr][ks * 32 + lg * 8]);
      const bfrag a1 = *reinterpret_cast<const bfrag*>(&a2b[16 + lr][ks * 32 + lg * 8]);
      const short* wp = w2T + ((size_t)((ks * 4 + lg) * 128) + n0w + lr) * 8;
      const bfrag bb0 = *reinterpret_cast<const bfrag*>(wp);
      const bfrag bb1 = *reinterpret_cast<const bfrag*>(wp + 16 * 8);
      acc[0][0] = __builtin_amdgcn_mfma_f32_16x16x32_bf16(a0, bb0, acc[0][0], 0, 0, 0);
      acc[1][0] = __builtin_amdgcn_mfma_f32_16x16x32_bf16(a1, bb0, acc[1][0], 0, 0, 0);
      acc[0][1] = __builtin_amdgcn_mfma_f32_16x16x32_bf16(a0, bb1, acc[0][1], 0, 0, 0);
      acc[1][1] = __builtin_amdgcn_mfma_f32_16x16x32_bf16(a1, bb1, acc[1][1], 0, 0, 0);
    }
    #pragma unroll
    for (int mt = 0; mt < 2; ++mt)
      #pragma unroll
      for (int nt = 0; nt < 2; ++nt)
        #pragma unroll
        for (int r = 0; r < 4; ++r) {
          const float v = acc[mt][nt][r];
          const size_t grow = (size_t)(n0 + mt * 16 + lg * 4 + r);
          const int    gcol = n0w + nt * 16 + lr;
          if constexpr (OUTBF) {
            ((short*)out_)[grow * DD + gcol] = f2bf(v);
          } else {
            __builtin_nontemporal_store(v, (float*)out_ + grow * DD + gcol);
          }
        }
  }
}

extern "C" void kernel_launch(void* const* d_in, const int* in_sizes, int n_in,
                              void* d_out, int out_size, void* d_ws, size_t ws_size,
                              hipStream_t stream) {
  const float* features = (const float*)d_in[0];
  const float* edge     = (const float*)d_in[1];
  const float* timef    = (const float*)d_in[2];
  const float* W1       = (const float*)d_in[3];
  const float* b1       = (const float*)d_in[4];
  const float* W2       = (const float*)d_in[5];
  const float* b2       = (const float*)d_in[6];
  const int*   idx      = (const int*)d_in[7];
  float* outp = (float*)d_out;

  short* wT     = (short*)d_ws;
  short* tmp    = (short*)((char*)d_ws + TMP_OFF_B);
  short* featbf = (short*)((char*)d_ws + FBF_OFF_B);

  dim3 block(256);

  prep_all<<<dim3(FBF_BLOCKS + PREP_BLOCKS), block, 0, stream>>>(
      features, featbf, W1, W2, wT);

  // layer 0: featbf -> tmp (bf16)
  tgn<true><<<dim3(GRID), block, 0, stream>>>(
      featbf, edge, timef, wT, b1, b2, idx, tmp);

  // layer 1: tmp -> out (f32)
  tgn<false><<<dim3(GRID), block, 0, stream>>>(
      tmp,
      edge  + (size_t)NN * KK * DEE,
      timef + (size_t)NN * KK * DTT,
      wT + WLAYER_SH,
      b1 + DD,
      b2 + DD,
      idx + (size_t)NN * KK,
      outp);
}